// Round 20
// baseline (701.215 us; speedup 1.0000x reference)
//
#include <hip/hip_runtime.h>
#include <math.h>

// ---------------------------------------------------------------------------
// DiscriminatorLSTM: B=128, T=64, FEAT=4096, FUSION=1024, H=1024, C=2
//
// r13/r14: all GEMMs single-product f16 MFMA (absmax unchanged 2e-3).
// r17/r18: BK=64 both GEMMs; bias folded; Gxp per-gate planes (write-amp fix).
// r20: (1) phase A uses BN=64 tile (grid 512->1024 WGs = 4 blocks/CU) —
//          counters showed occupancy-starvation (22%, >50% idle cycles),
//          not bandwidth (690 GB/s at 11% HBM).
//      (2) r19's lstm W-prefetch reverted (neutral-to-negative).
//
// prep:    cvt_f16 x2 ; prep_misc (out=b_cls broadcast, bsum=b_ih+b_hh)
// Phase A: F16 = f16(relu(X @ W_feat^T + b_feat))   (BN=64, X f32 cvt on fly)
// Phase B: Gxp(f16, 4 planes) = F16 @ Wih16^T + bsum  (BN=128)
// pack_whh3 (AFTER B): W_hh -> 16-col f16 B-frag pack
// Phase C: 64x lstm_step (f16 single-product, r18-proven)
//
// History: r10 grid.sync 4.6x slower; r11 XCD swizzle worse; r15 GLDS worse;
//          r19 W-prefetch neutral.
//
// ws layout (sizes + liveness verified):
//   [0,16M)   F16 (8192x1024 u16)   | after B: Wf f16 pack [0,8M)
//   [16,24M)  Wih16 (4096x1024 u16) | after B: hfrag @16M (512K dbuf), c @17M
//   [24,32M)  Wf16 (1024x4096 u16)  | dead after phase A
//   [32,96M)  Gxp u16 (4 planes x 8192x1024, 16 MB each)
//   [100M]    bsum (4096 f32, 16 KB)
// ---------------------------------------------------------------------------

typedef __attribute__((ext_vector_type(8))) short short8v;   // 8 x 16-bit
typedef __attribute__((ext_vector_type(4))) float f32x4;
typedef unsigned short u16;

#define HF2_BUF 262144   // one h-frag buffer: 8 mt x 32 kc x 64 lanes x 16B
#define HF2_MT  32768    // per m-tile: 32 kc x 1 KB
#define GX_PLANE 8388608u // 8192*1024 elements per gate plane

__device__ __forceinline__ short f2h(float f) {  // RNE f32->f16
    return __builtin_bit_cast(short, (_Float16)f);
}
__device__ __forceinline__ float h2f(u16 h) {
    return (float)__builtin_bit_cast(_Float16, (short)h);
}

// ---------------- elementwise f32 -> f16 convert ---------------------------
__global__ void cvt_f16(const float* __restrict__ src, u16* __restrict__ d, int n4) {
    int i = blockIdx.x * blockDim.x + threadIdx.x;
    if (i >= n4) return;
    float4 v = ((const float4*)src)[i];
    ushort4 o;
    o.x = (u16)f2h(v.x); o.y = (u16)f2h(v.y);
    o.z = (u16)f2h(v.z); o.w = (u16)f2h(v.w);
    ((ushort4*)d)[i] = o;
}

// out[0..16383] = b_cls[i&1]; bsum[0..4095] = b_ih + b_hh
__global__ void prep_misc(float* __restrict__ out, const float* __restrict__ b_cls,
                          const float* __restrict__ b_ih, const float* __restrict__ b_hh,
                          float* __restrict__ bsum) {
    int i = blockIdx.x * blockDim.x + threadIdx.x;
    if (i < 16384) out[i] = b_cls[i & 1];
    if (i < 4096)  bsum[i] = b_ih[i] + b_hh[i];
}

// ------------------- f16 MFMA GEMM  (C = A @ B^T) --------------------------
// 128x(BN) tile, BK templated, 4 waves. N64: BN=64, waves 2x2 each 64x32
// (acc[4][2]); else BN=128, waves 2x2 each 64x64 (acc[4][4]).
// LDS fragment swizzle p=(row^(koct<<1))|(koct<<4) [r9-proven conflict-free].
// OUT_F16: row-major u16. OUT_PLANES: per-gate-plane time-major u16.
template<int BK, bool N64, bool A_PRE16, bool RELU, bool OUT_F16, bool OUT_PLANES>
__global__ __launch_bounds__(256)
void gemm_f16(const float* __restrict__ Af,
              const u16* __restrict__ A16, int lda,
              const u16* __restrict__ B16, int ldb,
              const float* __restrict__ bias,
              float* __restrict__ C, u16* __restrict__ C16,
              int ldc, int K)
{
    constexpr int NH  = BK / 32;             // k-halves per iteration
    constexpr int NBF = N64 ? 4 : 8;         // B frag slots per k-half
    constexpr int NWN = N64 ? 2 : 4;         // n-frags per wave
    __shared__ short8v As[NH * 8][64];
    __shared__ short8v Bs[NH * NBF][64];

    const int tid = threadIdx.x;
    const int l   = tid & 63;
    const int w   = tid >> 6;
    const int wm  = w & 1, wn = w >> 1;
    const int bm  = blockIdx.x * 128;
    const int bn  = blockIdx.y * (N64 ? 64 : 128);

    const int sm    = tid >> 2;
    const int sk8   = (tid & 3) * 8;
    const int koct_s = sk8 >> 3;
    const int slane = ((sm & 15) ^ (koct_s << 1)) | (koct_s << 4);  // swizzled
    const int smf   = sm >> 4;
    const int lsw   = ((l & 15) ^ ((l >> 4) << 1)) | (l & 48);      // read side

    f32x4 acc[4][NWN];
#pragma unroll
    for (int i = 0; i < 4; ++i)
#pragma unroll
        for (int j = 0; j < NWN; ++j)
#pragma unroll
            for (int r = 0; r < 4; ++r) acc[i][j][r] = 0.f;

    for (int k0 = 0; k0 < K; k0 += BK) {
#pragma unroll
        for (int h = 0; h < NH; ++h) {
            const int kk = k0 + h * 32 + sk8;
            if constexpr (A_PRE16) {
                As[h * 8 + smf][slane]     = *(const short8v*)(A16 + (size_t)(bm + sm) * lda + kk);
                As[h * 8 + smf + 4][slane] = *(const short8v*)(A16 + (size_t)(bm + sm + 64) * lda + kk);
            } else {
                float fa[8], fb[8];
                const float* p0 = Af + (size_t)(bm + sm) * lda + kk;
                const float* p1 = Af + (size_t)(bm + sm + 64) * lda + kk;
                *(float4*)(fa)     = *(const float4*)(p0);
                *(float4*)(fa + 4) = *(const float4*)(p0 + 4);
                *(float4*)(fb)     = *(const float4*)(p1);
                *(float4*)(fb + 4) = *(const float4*)(p1 + 4);
                short8v ha, hb;
#pragma unroll
                for (int e = 0; e < 8; ++e) { ha[e] = f2h(fa[e]); hb[e] = f2h(fb[e]); }
                As[h * 8 + smf][slane]     = ha;
                As[h * 8 + smf + 4][slane] = hb;
            }
            if constexpr (N64) {
                // B tile is 64 rows: one store/thread (rows sm 0..63)
                Bs[h * NBF + smf][slane] = *(const short8v*)(B16 + (size_t)(bn + sm) * ldb + kk);
            } else {
                Bs[h * NBF + smf][slane]     = *(const short8v*)(B16 + (size_t)(bn + sm) * ldb + kk);
                Bs[h * NBF + smf + 4][slane] = *(const short8v*)(B16 + (size_t)(bn + sm + 64) * ldb + kk);
            }
        }
        __syncthreads();

#pragma unroll
        for (int h = 0; h < NH; ++h) {
            short8v a[4];
#pragma unroll
            for (int i = 0; i < 4; ++i) a[i] = As[h * 8 + wm * 4 + i][lsw];
#pragma unroll
            for (int j = 0; j < NWN; ++j) {
                const short8v b = Bs[h * NBF + wn * NWN + j][lsw];
#pragma unroll
                for (int i = 0; i < 4; ++i)
                    acc[i][j] = __builtin_amdgcn_mfma_f32_16x16x32_f16(a[i], b, acc[i][j], 0, 0, 0);
            }
        }
        __syncthreads();
    }

    const int row0 = bm + wm * 64 + (l >> 4) * 4;
    const int col0 = bn + wn * (NWN * 16) + (l & 15);
#pragma unroll
    for (int i = 0; i < 4; ++i) {
#pragma unroll
        for (int j = 0; j < NWN; ++j) {
            const int col = col0 + j * 16;
            const float bs = bias[col];
#pragma unroll
            for (int r = 0; r < 4; ++r) {
                const int row = row0 + i * 16 + r;
                float v = acc[i][j][r] + bs;
                if (RELU) v = fmaxf(v, 0.f);
                if (OUT_F16) {
                    C16[(size_t)row * ldc + col] = (u16)f2h(v);
                } else if (OUT_PLANES) {
                    // row = b*64+t -> rr = t*128+b ; plane = col>>10
                    const size_t rr = (size_t)(row & 63) * 128 + (row >> 6);
                    C16[(size_t)(col >> 10) * GX_PLANE + rr * 1024 + (col & 1023)]
                        = (u16)f2h(v);
                } else {
                    C[(size_t)row * ldc + col] = v;
                }
            }
        }
    }
}

// ----------- W_hh -> 16-col f16 B-fragment pre-pack (8 MB) -----------------
__global__ void pack_whh3(const float* __restrict__ W, char* __restrict__ Wf) {
    int gid = blockIdx.x * blockDim.x + threadIdx.x;   // < 524288
    int l = gid & 63, fid = gid >> 6;                  // fid < 8192
    int kcl = fid & 15, kh = (fid >> 4) & 1, ngrp = (fid >> 5) & 63, g = fid >> 11;
    int n = g * 1024 + ngrp * 16 + (l & 15);
    int k = kh * 512 + kcl * 32 + (l >> 4) * 8;
    const float* src = W + (size_t)n * 1024 + k;
    short8v v16;
#pragma unroll
    for (int e = 0; e < 8; ++e) v16[e] = f2h(src[e]);
    *(short8v*)(Wf + (size_t)fid * 1024 + (size_t)l * 16) = v16;
}

// --------------------------- fused LSTM step (f16, r18-proven) -------------
// 256 WGs x 512 thr. WG (mh = bid>>6, ngrp = bid&63): rows mh*32..+32,
// per-gate cols ngrp*16..+16. Wave w: gate g=w&3, K-half kh=w>>2.
// Single-product f16: 2 m-frags x 16 kcl = 32 MFMA/wave (4 indep chains).
// Gxp: 4 per-gate planes (bias pre-folded); cell loads early-issued.
__global__ __launch_bounds__(512)
void lstm_step(const u16* __restrict__ Gxp,
               const char*  __restrict__ Wf,
               char*        __restrict__ hfrag,
               float*       __restrict__ c,
               const float* __restrict__ Wc,
               float*       __restrict__ out,
               int t)
{
    __shared__ short8v Hs[64][64];           // 64 KB: s = mf*32 + kc
    __shared__ float gates_s[2][4][32][16];  // 16 KB
    __shared__ float h_s[32][16];            // 2 KB
    __shared__ float Wc_s[2][16];

    const int tid = threadIdx.x, bid = blockIdx.x;
    const int w = tid >> 6, l = tid & 63;
    const int g = w & 3, kh = w >> 2;
    const int ngrp = bid & 63, mh = bid >> 6;

    // ---- early-issue cell inputs (complete under staging/barrier) ----
    const int r_c  = tid >> 4;
    const int cw_c = tid & 15;
    const int row_c = mh * 32 + r_c;
    const int col_c = ngrp * 16 + cw_c;
    const u16* gp = Gxp + ((size_t)t * 128 + row_c) * 1024 + col_c;
    const u16 gv0 = gp[0];
    const u16 gv1 = gp[GX_PLANE];
    const u16 gv2 = gp[2u * GX_PLANE];
    const u16 gv3 = gp[3u * GX_PLANE];
    const size_t cidx = (size_t)row_c * 1024 + col_c;
    const float cp = (t > 0) ? c[cidx] : 0.f;

    if (tid < 32) Wc_s[tid >> 4][tid & 15] =
        Wc[(size_t)(tid >> 4) * 1024 + ngrp * 16 + (tid & 15)];

    const int lhi = l >> 4;
    const int llo = l & 15;

    f32x4 aE0, aO0, aE1, aO1;
#pragma unroll
    for (int r = 0; r < 4; ++r) { aE0[r] = 0.f; aO0[r] = 0.f; aE1[r] = 0.f; aO1[r] = 0.f; }

    if (t > 0) {
        // stage h f16 fragments for m_tiles {2mh, 2mh+1}: 64 slots x 1 KB
        const char* hbase = hfrag + ((t - 1) & 1) * HF2_BUF;
#pragma unroll
        for (int it = 0; it < 8; ++it) {
            const int u  = tid + it * 512;      // 0..4095
            const int s  = u >> 6;              // mf = s>>5, kc = s&31
            const int ln = u & 63;
            Hs[s][ln] = *(const short8v*)(hbase
                        + (size_t)(2 * mh + (s >> 5)) * HF2_MT
                        + (size_t)(s & 31) * 1024 + (size_t)ln * 16);
        }
        __syncthreads();

        const char* wb = Wf + (size_t)((g * 64 + ngrp) * 2 + kh) * 16384 + (size_t)l * 16;
#pragma unroll
        for (int kcl = 0; kcl < 16; kcl += 2) {
            const short8v b0 = *(const short8v*)(wb + kcl * 1024);
            const short8v b1 = *(const short8v*)(wb + (kcl + 1) * 1024);
            const int kc0 = kh * 16 + kcl;
            aE0 = __builtin_amdgcn_mfma_f32_16x16x32_f16(Hs[kc0][l],      b0, aE0, 0, 0, 0);
            aE1 = __builtin_amdgcn_mfma_f32_16x16x32_f16(Hs[32 + kc0][l], b0, aE1, 0, 0, 0);
            aO0 = __builtin_amdgcn_mfma_f32_16x16x32_f16(Hs[kc0 + 1][l],      b1, aO0, 0, 0, 0);
            aO1 = __builtin_amdgcn_mfma_f32_16x16x32_f16(Hs[32 + kc0 + 1][l], b1, aO1, 0, 0, 0);
        }
    }

    // partial gate tiles -> LDS (zeros at t==0); D: col=l&15, row=lhi*4+r
#pragma unroll
    for (int r = 0; r < 4; ++r) {
        gates_s[kh][g][lhi * 4 + r][llo]      = aE0[r] + aO0[r];
        gates_s[kh][g][16 + lhi * 4 + r][llo] = aE1[r] + aO1[r];
    }
    __syncthreads();

    // LSTM cell: 512 threads = 32 rows x 16 cols, one element each
    {
        float gate[4];
        gate[0] = h2f(gv0); gate[1] = h2f(gv1);
        gate[2] = h2f(gv2); gate[3] = h2f(gv3);
#pragma unroll
        for (int gg = 0; gg < 4; ++gg)
            gate[gg] += gates_s[0][gg][r_c][cw_c] + gates_s[1][gg][r_c][cw_c];
        float ig = 1.f / (1.f + __expf(-gate[0]));
        float fg = 1.f / (1.f + __expf(-gate[1]));
        float gg = tanhf(gate[2]);
        float og = 1.f / (1.f + __expf(-gate[3]));
        float cn = fg * cp + ig * gg;
        float hn = og * tanhf(cn);
        c[cidx] = cn;
        h_s[r_c][cw_c] = hn;

        // classifier partial: reduce over 16 cols (cw), then atomicAdd
        float s0 = hn * Wc_s[0][cw_c];
        float s1 = hn * Wc_s[1][cw_c];
#pragma unroll
        for (int off = 8; off > 0; off >>= 1) {
            s0 += __shfl_xor(s0, off);
            s1 += __shfl_xor(s1, off);
        }
        if (cw_c == 0) {
            float* o = out + ((size_t)row_c * 64 + t) * 2;
            atomicAdd(o,     s0);
            atomicAdd(o + 1, s1);
        }
    }
    __syncthreads();

    // h-fragment write (f16): WG owns kc = ngrp>>1, koct pair (ngrp&1)*2..+1,
    // m_tiles 2mh..2mh+1. 64 threads x 16B chunks.
    if (tid < 64) {
        const int idx16  = tid & 15;
        const int koct_h = (tid >> 4) & 1;
        const int mt_l   = (tid >> 5) & 1;
        const int lane   = idx16 | (((ngrp & 1) * 2 + koct_h) << 4);
        short8v v;
#pragma unroll
        for (int e = 0; e < 8; ++e)
            v[e] = f2h(h_s[mt_l * 16 + idx16][koct_h * 8 + e]);
        char* dst = hfrag + (t & 1) * HF2_BUF
                  + (size_t)(2 * mh + mt_l) * HF2_MT
                  + (size_t)(ngrp >> 1) * 1024 + (size_t)lane * 16;
        *(short8v*)dst = v;
    }
}

// ---------------------------------------------------------------------------
extern "C" void kernel_launch(void* const* d_in, const int* in_sizes, int n_in,
                              void* d_out, int out_size, void* d_ws, size_t ws_size,
                              hipStream_t stream) {
    const float* x      = (const float*)d_in[0];
    const float* W_feat = (const float*)d_in[1];
    const float* b_feat = (const float*)d_in[2];
    const float* W_ih   = (const float*)d_in[3];
    const float* b_ih   = (const float*)d_in[4];
    const float* W_hh   = (const float*)d_in[5];
    const float* b_hh   = (const float*)d_in[6];
    const float* W_cls  = (const float*)d_in[7];
    const float* b_cls  = (const float*)d_in[8];
    float* out = (float*)d_out;

    char* ws = (char*)d_ws;
    u16*  F16   = (u16*)ws;                    // [0,16M)  8192x1024 u16 f16
    u16*  Wih16 = (u16*)(ws + 16777216);       // [16,24M) 4096x1024 u16 f16
    u16*  Wf16  = (u16*)(ws + 25165824);       // [24,32M) 1024x4096 u16 f16
    u16*  Gxp   = (u16*)(ws + 33554432);       // [32,96M) 4 planes x 16 MB
    float* bsum = (float*)(ws + 104857600);    // [100M, +16K) b_ih + b_hh
    char* Wf    = ws;                          // [0,8M)   whh f16 pack (post-B)
    char* hfrag = ws + 16777216;               // [16,16.5M) post-B (512K dbuf)
    float* c    = (float*)(ws + 17825792);     // [17,17.5M) post-B

    // prep: both weight matrices are 4,194,304 floats = 1,048,576 float4
    cvt_f16<<<dim3(4096), dim3(256), 0, stream>>>(W_feat, Wf16, 1048576);
    cvt_f16<<<dim3(4096), dim3(256), 0, stream>>>(W_ih, Wih16, 1048576);
    prep_misc<<<dim3(64), dim3(256), 0, stream>>>(out, b_cls, b_ih, b_hh, bsum);

    // Phase A: F16 = f16(relu(X @ W_feat^T + b_feat))  M=8192 N=1024 K=4096
    // BN=64 -> grid 64x16 = 1024 WGs = 4 blocks/CU (was 2: occupancy-starved)
    gemm_f16<64, true, false, true, true, false>
        <<<dim3(64, 16), 256, 0, stream>>>(
            x, nullptr, 4096, Wf16, 4096, b_feat,
            nullptr, F16, 1024, 4096);

    // Phase B: Gxp = F16 @ Wih16^T + bsum   M=8192 N=4096 K=1024, 4 planes
    gemm_f16<64, false, true, false, false, true>
        <<<dim3(64, 32), 256, 0, stream>>>(
            nullptr, F16, 1024, Wih16, 1024, bsum,
            nullptr, Gxp, 4096, 1024);

    // pack W_hh f16 fragments AFTER phase B (aliases dead F16 region)
    pack_whh3<<<dim3(2048), dim3(256), 0, stream>>>(W_hh, Wf);

    // Phase C: 64 fused recurrent steps (per-step launches; see r10 note)
    for (int t = 0; t < 64; ++t) {
        lstm_step<<<dim3(256), dim3(512), 0, stream>>>(
            Gxp, Wf, hfrag, c, W_cls, out, t);
    }
}

// Round 21
// 655.914 us; speedup vs baseline: 1.0691x; 1.0691x over previous
//
#include <hip/hip_runtime.h>
#include <math.h>

// ---------------------------------------------------------------------------
// DiscriminatorLSTM: B=128, T=64, FEAT=4096, FUSION=1024, H=1024, C=2
//
// r13/r14: all GEMMs single-product f16 MFMA (absmax unchanged 2e-3).
// r17/r18: BK=64 both GEMMs; bias folded; Gxp per-gate planes (write-amp fix).
// r21: phase A runs a 512-thread (8-wave) variant of the SAME 128x128xBK64
//      tile — 16 waves/CU (was 8) for latency hiding, traffic unchanged.
//      (r20's BN=64 reverted: occupancy rose but X-fetch doubled, net loss.)
//
// prep:    cvt_f16 x2 ; prep_misc (out=b_cls broadcast, bsum=b_ih+b_hh)
// Phase A: F16 = f16(relu(X @ W_feat^T + b_feat))   (512-thr, X f32 cvt)
// Phase B: Gxp(f16, 4 planes) = F16 @ Wih16^T + bsum  (256-thr, r18-proven)
// pack_whh3 (AFTER B): W_hh -> 16-col f16 B-frag pack
// Phase C: 64x lstm_step (f16 single-product, r18-proven)
//
// History: r10 grid.sync 4.6x slower; r11 XCD swizzle worse; r15 GLDS worse;
//          r19 W-prefetch neutral; r20 BN=64 worse (2x X fetch).
//
// ws layout (sizes + liveness verified):
//   [0,16M)   F16 (8192x1024 u16)   | after B: Wf f16 pack [0,8M)
//   [16,24M)  Wih16 (4096x1024 u16) | after B: hfrag @16M (512K dbuf), c @17M
//   [24,32M)  Wf16 (1024x4096 u16)  | dead after phase A
//   [32,96M)  Gxp u16 (4 planes x 8192x1024, 16 MB each)
//   [100M]    bsum (4096 f32, 16 KB)
// ---------------------------------------------------------------------------

typedef __attribute__((ext_vector_type(8))) short short8v;   // 8 x 16-bit
typedef __attribute__((ext_vector_type(4))) float f32x4;
typedef unsigned short u16;

#define HF2_BUF 262144   // one h-frag buffer: 8 mt x 32 kc x 64 lanes x 16B
#define HF2_MT  32768    // per m-tile: 32 kc x 1 KB
#define GX_PLANE 8388608u // 8192*1024 elements per gate plane

__device__ __forceinline__ short f2h(float f) {  // RNE f32->f16
    return __builtin_bit_cast(short, (_Float16)f);
}
__device__ __forceinline__ float h2f(u16 h) {
    return (float)__builtin_bit_cast(_Float16, (short)h);
}

// ---------------- elementwise f32 -> f16 convert ---------------------------
__global__ void cvt_f16(const float* __restrict__ src, u16* __restrict__ d, int n4) {
    int i = blockIdx.x * blockDim.x + threadIdx.x;
    if (i >= n4) return;
    float4 v = ((const float4*)src)[i];
    ushort4 o;
    o.x = (u16)f2h(v.x); o.y = (u16)f2h(v.y);
    o.z = (u16)f2h(v.z); o.w = (u16)f2h(v.w);
    ((ushort4*)d)[i] = o;
}

// out[0..16383] = b_cls[i&1]; bsum[0..4095] = b_ih + b_hh
__global__ void prep_misc(float* __restrict__ out, const float* __restrict__ b_cls,
                          const float* __restrict__ b_ih, const float* __restrict__ b_hh,
                          float* __restrict__ bsum) {
    int i = blockIdx.x * blockDim.x + threadIdx.x;
    if (i < 16384) out[i] = b_cls[i & 1];
    if (i < 4096)  bsum[i] = b_ih[i] + b_hh[i];
}

// ---------- phase A: 512-thread f16 MFMA GEMM, C=A@B^T, relu, f16 out ------
// BM=128, BN=128, BK=64. 8 waves 2m x 4n, each 64x32 (acc[4][2]).
// Staging: 512 threads = 1 slot-store/thread/k-half (sm=tid>>2 spans 128 rows).
// LDS fragment swizzle p=(row^(koct<<1))|(koct<<4) [r9-proven conflict-free].
__global__ __launch_bounds__(512)
void gemm_a512(const float* __restrict__ Af, int lda,
               const u16* __restrict__ B16, int ldb,
               const float* __restrict__ bias,
               u16* __restrict__ C16, int ldc, int K)
{
    __shared__ short8v As[16][64];   // [h*8 + mf][lane]
    __shared__ short8v Bs[16][64];

    const int tid = threadIdx.x;
    const int l   = tid & 63;
    const int w   = tid >> 6;        // 0..7
    const int wm  = w & 1, wn = w >> 1;   // wn 0..3
    const int bm  = blockIdx.x * 128, bn = blockIdx.y * 128;

    const int sm    = tid >> 2;              // 0..127
    const int sk8   = (tid & 3) * 8;
    const int koct_s = sk8 >> 3;
    const int slane = ((sm & 15) ^ (koct_s << 1)) | (koct_s << 4);
    const int smf   = sm >> 4;               // 0..7
    const int lsw   = ((l & 15) ^ ((l >> 4) << 1)) | (l & 48);

    f32x4 acc[4][2];
#pragma unroll
    for (int i = 0; i < 4; ++i)
#pragma unroll
        for (int j = 0; j < 2; ++j)
#pragma unroll
            for (int r = 0; r < 4; ++r) acc[i][j][r] = 0.f;

    for (int k0 = 0; k0 < K; k0 += 64) {
#pragma unroll
        for (int h = 0; h < 2; ++h) {
            const int kk = k0 + h * 32 + sk8;
            float fa[8];
            const float* p0 = Af + (size_t)(bm + sm) * lda + kk;
            *(float4*)(fa)     = *(const float4*)(p0);
            *(float4*)(fa + 4) = *(const float4*)(p0 + 4);
            short8v ha;
#pragma unroll
            for (int e = 0; e < 8; ++e) ha[e] = f2h(fa[e]);
            As[h * 8 + smf][slane] = ha;
            Bs[h * 8 + smf][slane] = *(const short8v*)(B16 + (size_t)(bn + sm) * ldb + kk);
        }
        __syncthreads();

#pragma unroll
        for (int h = 0; h < 2; ++h) {
            short8v a[4];
#pragma unroll
            for (int i = 0; i < 4; ++i) a[i] = As[h * 8 + wm * 4 + i][lsw];
#pragma unroll
            for (int j = 0; j < 2; ++j) {
                const short8v b = Bs[h * 8 + wn * 2 + j][lsw];
#pragma unroll
                for (int i = 0; i < 4; ++i)
                    acc[i][j] = __builtin_amdgcn_mfma_f32_16x16x32_f16(a[i], b, acc[i][j], 0, 0, 0);
            }
        }
        __syncthreads();
    }

    const int row0 = bm + wm * 64 + (l >> 4) * 4;
    const int col0 = bn + wn * 32 + (l & 15);
#pragma unroll
    for (int i = 0; i < 4; ++i) {
#pragma unroll
        for (int j = 0; j < 2; ++j) {
            const int col = col0 + j * 16;
            const float bs = bias[col];
#pragma unroll
            for (int r = 0; r < 4; ++r) {
                const int row = row0 + i * 16 + r;
                float v = fmaxf(acc[i][j][r] + bs, 0.f);
                C16[(size_t)row * ldc + col] = (u16)f2h(v);
            }
        }
    }
}

// ------------- phase B: 256-thread f16 MFMA GEMM (r18-proven) --------------
// 128x128, BK=64, A pre-f16, out = per-gate planes time-major.
__global__ __launch_bounds__(256)
void gemm_b(const u16* __restrict__ A16, int lda,
            const u16* __restrict__ B16, int ldb,
            const float* __restrict__ bias,
            u16* __restrict__ C16, int K)
{
    __shared__ short8v As[16][64];
    __shared__ short8v Bs[16][64];

    const int tid = threadIdx.x;
    const int l   = tid & 63;
    const int w   = tid >> 6;
    const int wm  = w & 1, wn = w >> 1;
    const int bm  = blockIdx.x * 128, bn = blockIdx.y * 128;

    const int sm    = tid >> 2;
    const int sk8   = (tid & 3) * 8;
    const int koct_s = sk8 >> 3;
    const int slane = ((sm & 15) ^ (koct_s << 1)) | (koct_s << 4);
    const int smf   = sm >> 4;
    const int lsw   = ((l & 15) ^ ((l >> 4) << 1)) | (l & 48);

    f32x4 acc[4][4];
#pragma unroll
    for (int i = 0; i < 4; ++i)
#pragma unroll
        for (int j = 0; j < 4; ++j)
#pragma unroll
            for (int r = 0; r < 4; ++r) acc[i][j][r] = 0.f;

    for (int k0 = 0; k0 < K; k0 += 64) {
#pragma unroll
        for (int h = 0; h < 2; ++h) {
            const int kk = k0 + h * 32 + sk8;
            As[h * 8 + smf][slane]     = *(const short8v*)(A16 + (size_t)(bm + sm) * lda + kk);
            As[h * 8 + smf + 4][slane] = *(const short8v*)(A16 + (size_t)(bm + sm + 64) * lda + kk);
            Bs[h * 8 + smf][slane]     = *(const short8v*)(B16 + (size_t)(bn + sm) * ldb + kk);
            Bs[h * 8 + smf + 4][slane] = *(const short8v*)(B16 + (size_t)(bn + sm + 64) * ldb + kk);
        }
        __syncthreads();

#pragma unroll
        for (int h = 0; h < 2; ++h) {
            short8v a[4];
#pragma unroll
            for (int i = 0; i < 4; ++i) a[i] = As[h * 8 + wm * 4 + i][lsw];
#pragma unroll
            for (int j = 0; j < 4; ++j) {
                const short8v b = Bs[h * 8 + wn * 4 + j][lsw];
#pragma unroll
                for (int i = 0; i < 4; ++i)
                    acc[i][j] = __builtin_amdgcn_mfma_f32_16x16x32_f16(a[i], b, acc[i][j], 0, 0, 0);
            }
        }
        __syncthreads();
    }

    const int row0 = bm + wm * 64 + (l >> 4) * 4;
    const int col0 = bn + wn * 64 + (l & 15);
#pragma unroll
    for (int i = 0; i < 4; ++i) {
#pragma unroll
        for (int j = 0; j < 4; ++j) {
            const int col = col0 + j * 16;
            const float bs = bias[col];
#pragma unroll
            for (int r = 0; r < 4; ++r) {
                const int row = row0 + i * 16 + r;
                const float v = acc[i][j][r] + bs;
                const size_t rr = (size_t)(row & 63) * 128 + (row >> 6);
                C16[(size_t)(col >> 10) * GX_PLANE + rr * 1024 + (col & 1023)]
                    = (u16)f2h(v);
            }
        }
    }
}

// ----------- W_hh -> 16-col f16 B-fragment pre-pack (8 MB) -----------------
__global__ void pack_whh3(const float* __restrict__ W, char* __restrict__ Wf) {
    int gid = blockIdx.x * blockDim.x + threadIdx.x;   // < 524288
    int l = gid & 63, fid = gid >> 6;                  // fid < 8192
    int kcl = fid & 15, kh = (fid >> 4) & 1, ngrp = (fid >> 5) & 63, g = fid >> 11;
    int n = g * 1024 + ngrp * 16 + (l & 15);
    int k = kh * 512 + kcl * 32 + (l >> 4) * 8;
    const float* src = W + (size_t)n * 1024 + k;
    short8v v16;
#pragma unroll
    for (int e = 0; e < 8; ++e) v16[e] = f2h(src[e]);
    *(short8v*)(Wf + (size_t)fid * 1024 + (size_t)l * 16) = v16;
}

// --------------------------- fused LSTM step (f16, r18-proven) -------------
__global__ __launch_bounds__(512)
void lstm_step(const u16* __restrict__ Gxp,
               const char*  __restrict__ Wf,
               char*        __restrict__ hfrag,
               float*       __restrict__ c,
               const float* __restrict__ Wc,
               float*       __restrict__ out,
               int t)
{
    __shared__ short8v Hs[64][64];           // 64 KB: s = mf*32 + kc
    __shared__ float gates_s[2][4][32][16];  // 16 KB
    __shared__ float h_s[32][16];            // 2 KB
    __shared__ float Wc_s[2][16];

    const int tid = threadIdx.x, bid = blockIdx.x;
    const int w = tid >> 6, l = tid & 63;
    const int g = w & 3, kh = w >> 2;
    const int ngrp = bid & 63, mh = bid >> 6;

    // ---- early-issue cell inputs (complete under staging/barrier) ----
    const int r_c  = tid >> 4;
    const int cw_c = tid & 15;
    const int row_c = mh * 32 + r_c;
    const int col_c = ngrp * 16 + cw_c;
    const u16* gp = Gxp + ((size_t)t * 128 + row_c) * 1024 + col_c;
    const u16 gv0 = gp[0];
    const u16 gv1 = gp[GX_PLANE];
    const u16 gv2 = gp[2u * GX_PLANE];
    const u16 gv3 = gp[3u * GX_PLANE];
    const size_t cidx = (size_t)row_c * 1024 + col_c;
    const float cp = (t > 0) ? c[cidx] : 0.f;

    if (tid < 32) Wc_s[tid >> 4][tid & 15] =
        Wc[(size_t)(tid >> 4) * 1024 + ngrp * 16 + (tid & 15)];

    const int lhi = l >> 4;
    const int llo = l & 15;

    f32x4 aE0, aO0, aE1, aO1;
#pragma unroll
    for (int r = 0; r < 4; ++r) { aE0[r] = 0.f; aO0[r] = 0.f; aE1[r] = 0.f; aO1[r] = 0.f; }

    if (t > 0) {
        // stage h f16 fragments for m_tiles {2mh, 2mh+1}: 64 slots x 1 KB
        const char* hbase = hfrag + ((t - 1) & 1) * HF2_BUF;
#pragma unroll
        for (int it = 0; it < 8; ++it) {
            const int u  = tid + it * 512;      // 0..4095
            const int s  = u >> 6;              // mf = s>>5, kc = s&31
            const int ln = u & 63;
            Hs[s][ln] = *(const short8v*)(hbase
                        + (size_t)(2 * mh + (s >> 5)) * HF2_MT
                        + (size_t)(s & 31) * 1024 + (size_t)ln * 16);
        }
        __syncthreads();

        const char* wb = Wf + (size_t)((g * 64 + ngrp) * 2 + kh) * 16384 + (size_t)l * 16;
#pragma unroll
        for (int kcl = 0; kcl < 16; kcl += 2) {
            const short8v b0 = *(const short8v*)(wb + kcl * 1024);
            const short8v b1 = *(const short8v*)(wb + (kcl + 1) * 1024);
            const int kc0 = kh * 16 + kcl;
            aE0 = __builtin_amdgcn_mfma_f32_16x16x32_f16(Hs[kc0][l],      b0, aE0, 0, 0, 0);
            aE1 = __builtin_amdgcn_mfma_f32_16x16x32_f16(Hs[32 + kc0][l], b0, aE1, 0, 0, 0);
            aO0 = __builtin_amdgcn_mfma_f32_16x16x32_f16(Hs[kc0 + 1][l],      b1, aO0, 0, 0, 0);
            aO1 = __builtin_amdgcn_mfma_f32_16x16x32_f16(Hs[32 + kc0 + 1][l], b1, aO1, 0, 0, 0);
        }
    }

    // partial gate tiles -> LDS (zeros at t==0); D: col=l&15, row=lhi*4+r
#pragma unroll
    for (int r = 0; r < 4; ++r) {
        gates_s[kh][g][lhi * 4 + r][llo]      = aE0[r] + aO0[r];
        gates_s[kh][g][16 + lhi * 4 + r][llo] = aE1[r] + aO1[r];
    }
    __syncthreads();

    // LSTM cell: 512 threads = 32 rows x 16 cols, one element each
    {
        float gate[4];
        gate[0] = h2f(gv0); gate[1] = h2f(gv1);
        gate[2] = h2f(gv2); gate[3] = h2f(gv3);
#pragma unroll
        for (int gg = 0; gg < 4; ++gg)
            gate[gg] += gates_s[0][gg][r_c][cw_c] + gates_s[1][gg][r_c][cw_c];
        float ig = 1.f / (1.f + __expf(-gate[0]));
        float fg = 1.f / (1.f + __expf(-gate[1]));
        float gg = tanhf(gate[2]);
        float og = 1.f / (1.f + __expf(-gate[3]));
        float cn = fg * cp + ig * gg;
        float hn = og * tanhf(cn);
        c[cidx] = cn;
        h_s[r_c][cw_c] = hn;

        // classifier partial: reduce over 16 cols (cw), then atomicAdd
        float s0 = hn * Wc_s[0][cw_c];
        float s1 = hn * Wc_s[1][cw_c];
#pragma unroll
        for (int off = 8; off > 0; off >>= 1) {
            s0 += __shfl_xor(s0, off);
            s1 += __shfl_xor(s1, off);
        }
        if (cw_c == 0) {
            float* o = out + ((size_t)row_c * 64 + t) * 2;
            atomicAdd(o,     s0);
            atomicAdd(o + 1, s1);
        }
    }
    __syncthreads();

    // h-fragment write (f16): WG owns kc = ngrp>>1, koct pair (ngrp&1)*2..+1,
    // m_tiles 2mh..2mh+1. 64 threads x 16B chunks.
    if (tid < 64) {
        const int idx16  = tid & 15;
        const int koct_h = (tid >> 4) & 1;
        const int mt_l   = (tid >> 5) & 1;
        const int lane   = idx16 | (((ngrp & 1) * 2 + koct_h) << 4);
        short8v v;
#pragma unroll
        for (int e = 0; e < 8; ++e)
            v[e] = f2h(h_s[mt_l * 16 + idx16][koct_h * 8 + e]);
        char* dst = hfrag + (t & 1) * HF2_BUF
                  + (size_t)(2 * mh + mt_l) * HF2_MT
                  + (size_t)(ngrp >> 1) * 1024 + (size_t)lane * 16;
        *(short8v*)dst = v;
    }
}

// ---------------------------------------------------------------------------
extern "C" void kernel_launch(void* const* d_in, const int* in_sizes, int n_in,
                              void* d_out, int out_size, void* d_ws, size_t ws_size,
                              hipStream_t stream) {
    const float* x      = (const float*)d_in[0];
    const float* W_feat = (const float*)d_in[1];
    const float* b_feat = (const float*)d_in[2];
    const float* W_ih   = (const float*)d_in[3];
    const float* b_ih   = (const float*)d_in[4];
    const float* W_hh   = (const float*)d_in[5];
    const float* b_hh   = (const float*)d_in[6];
    const float* W_cls  = (const float*)d_in[7];
    const float* b_cls  = (const float*)d_in[8];
    float* out = (float*)d_out;

    char* ws = (char*)d_ws;
    u16*  F16   = (u16*)ws;                    // [0,16M)  8192x1024 u16 f16
    u16*  Wih16 = (u16*)(ws + 16777216);       // [16,24M) 4096x1024 u16 f16
    u16*  Wf16  = (u16*)(ws + 25165824);       // [24,32M) 1024x4096 u16 f16
    u16*  Gxp   = (u16*)(ws + 33554432);       // [32,96M) 4 planes x 16 MB
    float* bsum = (float*)(ws + 104857600);    // [100M, +16K) b_ih + b_hh
    char* Wf    = ws;                          // [0,8M)   whh f16 pack (post-B)
    char* hfrag = ws + 16777216;               // [16,16.5M) post-B (512K dbuf)
    float* c    = (float*)(ws + 17825792);     // [17,17.5M) post-B

    // prep: both weight matrices are 4,194,304 floats = 1,048,576 float4
    cvt_f16<<<dim3(4096), dim3(256), 0, stream>>>(W_feat, Wf16, 1048576);
    cvt_f16<<<dim3(4096), dim3(256), 0, stream>>>(W_ih, Wih16, 1048576);
    prep_misc<<<dim3(64), dim3(256), 0, stream>>>(out, b_cls, b_ih, b_hh, bsum);

    // Phase A: F16 = f16(relu(X @ W_feat^T + b_feat))  M=8192 N=1024 K=4096
    // 512-thread variant: 16 waves/CU (was 8), same tile, same traffic.
    gemm_a512<<<dim3(64, 8), 512, 0, stream>>>(
        x, 4096, Wf16, 4096, b_feat, F16, 1024, 4096);

    // Phase B: Gxp = F16 @ Wih16^T + bsum   M=8192 N=4096 K=1024, 4 planes
    gemm_b<<<dim3(64, 32), 256, 0, stream>>>(
        F16, 1024, Wih16, 1024, bsum, Gxp, 1024);

    // pack W_hh f16 fragments AFTER phase B (aliases dead F16 region)
    pack_whh3<<<dim3(2048), dim3(256), 0, stream>>>(W_hh, Wf);

    // Phase C: 64 fused recurrent steps (per-step launches; see r10 note)
    for (int t = 0; t < 64; ++t) {
        lstm_step<<<dim3(256), dim3(512), 0, stream>>>(
            Gxp, Wf, hfrag, c, W_cls, out, t);
    }
}